// Round 6
// baseline (299.864 us; speedup 1.0000x reference)
//
#include <hip/hip_runtime.h>
#include <math.h>

typedef __bf16 bf16x8 __attribute__((ext_vector_type(8)));
typedef float  f32x4  __attribute__((ext_vector_type(4)));

#define NEGB   (-1.4426950408889634e30f)   // -1e30 * log2(e)  (log2-domain mask value)
#define SCALE2 (0.18033688011112042f)      // (1/sqrt(64)) * log2(e), folded into q

static __device__ __forceinline__ f32x4 mfma16(bf16x8 a, bf16x8 b, f32x4 c) {
    return __builtin_amdgcn_mfma_f32_16x16x32_bf16(a, b, c, 0, 0, 0);
}

// DPP row_ror (within 16-lane rows) — VALU-only cross-lane, no DS pipe
template <int CTRL>
static __device__ __forceinline__ float dppf(float x) {
    int xi = __builtin_bit_cast(int, x);
    int r = __builtin_amdgcn_update_dpp(xi, xi, CTRL, 0xf, 0xf, false);
    return __builtin_bit_cast(float, r);
}
static __device__ __forceinline__ float rowmax16(float x) {
    x = fmaxf(x, dppf<0x128>(x));
    x = fmaxf(x, dppf<0x124>(x));
    x = fmaxf(x, dppf<0x122>(x));
    x = fmaxf(x, dppf<0x121>(x));
    return x;
}
static __device__ __forceinline__ float rowsum16(float x) {
    x += dppf<0x128>(x);
    x += dppf<0x124>(x);
    x += dppf<0x122>(x);
    x += dppf<0x121>(x);
    return x;
}

// ---------------- prep: mask -> bitmask, W -> hi/lo bf16 fragment order ----------------
__global__ void prep_kernel(const int* __restrict__ mask,
                            const float* __restrict__ Wq, const float* __restrict__ Wk,
                            const float* __restrict__ Wv,
                            unsigned long long* __restrict__ mbits,
                            __bf16* __restrict__ Whi_t, __bf16* __restrict__ Wlo_t)
{
    const int tid = threadIdx.x;
    if (blockIdx.x < 1024) {
        const int row = blockIdx.x, wave = tid >> 6, lane = tid & 63;
        #pragma unroll
        for (int i = 0; i < 4; ++i) {
            int word = wave * 4 + i;
            int m = mask[row * 1024 + word * 64 + lane];
            unsigned long long b = __ballot(m != 0);
            if (lane == 0) mbits[row * 16 + word] = b;
        }
    } else {
        int idx = (blockIdx.x - 1024) * 256 + tid;          // 0..49151
        int lane = idx & 63, t = (idx >> 6) & 3, kc = (idx >> 8) & 7;
        int head = (idx >> 11) & 7, mat = idx >> 14;
        int quad = lane >> 4, ln = lane & 15;
        const float* W = (mat == 0 ? Wq : (mat == 1 ? Wk : Wv)) + head * 16384;
        bf16x8 hi, lo;
        #pragma unroll
        for (int j = 0; j < 8; ++j) {
            float w = W[(kc * 32 + quad * 8 + j) * 64 + t * 16 + ln];
            __bf16 hh = (__bf16)w;
            hi[j] = hh;
            lo[j] = (__bf16)(w - (float)hh);
        }
        *(bf16x8*)(Whi_t + (size_t)idx * 8) = hi;
        *(bf16x8*)(Wlo_t + (size_t)idx * 8) = lo;
    }
}

// ---------------- projKV ----------------
// grid (2 head-halves FAST, 256 rt): X gathered ONCE per block, 4-head inner loop.
// Output tiles in attn B-FRAGMENT order: plane[bh][mt], frag (g,lane) 16B at ((g)*64+lane)*16
//   K: g = mgrp*2 + dkchunk ; V: g = dvgrp*2 + mchunk
__global__ __launch_bounds__(256, 2) void projkv_kernel(
    const float* __restrict__ X,
    const __bf16* __restrict__ Whi_t, const __bf16* __restrict__ Wlo_t,
    unsigned char* __restrict__ khi_g, unsigned char* __restrict__ klo_g,
    unsigned char* __restrict__ vT_g)
{
    const int hh = blockIdx.x;     // 0..1
    const int rt = blockIdx.y;     // 0..255
    const int tid = threadIdx.x, wave = tid >> 6, lane = tid & 63;
    const int quad = lane >> 4, ln = lane & 15;

    __shared__ __align__(16) unsigned char SL[24576];   // khi | klo | v (one head at a time)

    // X A-frags, hi/lo split ONCE (rows = rt*64 + wave*16 + ln)
    const float* xr = X + ((size_t)(rt * 64 + wave * 16 + ln)) * 256;
    bf16x8 ahi[8], alo[8];
    #pragma unroll
    for (int kc = 0; kc < 8; ++kc) {
        f32x4 xa = *(const f32x4*)(xr + kc * 32 + quad * 8);
        f32x4 xb = *(const f32x4*)(xr + kc * 32 + quad * 8 + 4);
        #pragma unroll
        for (int j = 0; j < 4; ++j) {
            __bf16 h0 = (__bf16)xa[j]; ahi[kc][j] = h0; alo[kc][j] = (__bf16)(xa[j] - (float)h0);
            __bf16 h1 = (__bf16)xb[j]; ahi[kc][4 + j] = h1; alo[kc][4 + j] = (__bf16)(xb[j] - (float)h1);
        }
    }

    const int mt = rt & 15;
    const int b8 = (rt >> 4) * 8;

    for (int h4 = 0; h4 < 4; ++h4) {
        const int head = hh * 4 + h4;
        const __bf16* WhiK = Whi_t + ((size_t)(8 + head) * 2048) * 8;
        const __bf16* WloK = Wlo_t + ((size_t)(8 + head) * 2048) * 8;
        const __bf16* WhiV = Whi_t + ((size_t)(16 + head) * 2048) * 8;

        f32x4 kacc[4], vacc[4];
        #pragma unroll
        for (int t = 0; t < 4; ++t) { kacc[t] = (f32x4){0.f,0.f,0.f,0.f}; vacc[t] = kacc[t]; }

        #pragma unroll
        for (int kc = 0; kc < 8; ++kc) {
            #pragma unroll
            for (int t = 0; t < 4; ++t) {
                size_t fo = (size_t)((kc * 4 + t) * 64 + lane) * 8;
                bf16x8 bhiK = *(const bf16x8*)(WhiK + fo);
                bf16x8 bloK = *(const bf16x8*)(WloK + fo);
                bf16x8 bhiV = *(const bf16x8*)(WhiV + fo);
                kacc[t] = mfma16(ahi[kc], bhiK, kacc[t]);
                kacc[t] = mfma16(alo[kc], bhiK, kacc[t]);
                kacc[t] = mfma16(ahi[kc], bloK, kacc[t]);
                vacc[t] = mfma16(ahi[kc], bhiV, vacc[t]);
            }
        }

        // assemble B-fragment-ordered tiles in LDS
        #pragma unroll
        for (int tp = 0; tp < 4; ++tp) {
            #pragma unroll
            for (int r = 0; r < 4; ++r) {
                {   // K element (m = wave*16+quad*4+r, dk = tp*16+ln)
                    float val = kacc[tp][r];
                    __bf16 hhv = (__bf16)val;
                    __bf16 llv = (__bf16)(val - (float)hhv);
                    int off = ((wave * 2 + (tp >> 1)) * 64 +
                               ((tp & 1) * 2 + (ln >> 3)) * 16 + quad * 4 + r) * 16 +
                              (ln & 7) * 2;
                    *(__bf16*)(SL + off) = hhv;
                    *(__bf16*)(SL + 8192 + off) = llv;
                }
                {   // V element (m = wave*16+quad*4+r, dv = tp*16+ln)
                    int off = ((tp * 2 + (wave >> 1)) * 64 +
                               ((wave & 1) * 2 + (quad >> 1)) * 16 + ln) * 16 +
                              ((quad & 1) * 4 + r) * 2;
                    *(__bf16*)(SL + 16384 + off) = (__bf16)vacc[tp][r];
                }
            }
        }
        __syncthreads();

        const size_t tb = (size_t)((b8 + head) * 16 + mt) * 8192;
        #pragma unroll
        for (int i = 0; i < 2; ++i) {
            int c = (i * 256 + tid) * 16;
            *(uint4*)(khi_g + tb + c) = *(const uint4*)(SL + c);
            *(uint4*)(klo_g + tb + c) = *(const uint4*)(SL + 8192 + c);
            *(uint4*)(vT_g  + tb + c) = *(const uint4*)(SL + 16384 + c);
        }
        __syncthreads();   // SL reused by next head
    }
}

// ---------------- attn: fused Q-projection + flash attention, BARRIER-FREE ----------------
// block = 256 thr (4 waves x 32 q-rows), BM=128, grid (128 bh FAST, 8 qt)
// K/V frags read directly from global (L2); P + Q-transpose in per-wave LDS regions.
__global__ __launch_bounds__(256, 2) void attn_kernel(
    const float* __restrict__ X,
    const __bf16* __restrict__ Whi_t, const __bf16* __restrict__ Wlo_t,
    const unsigned char* __restrict__ khi_g, const unsigned char* __restrict__ klo_g,
    const unsigned char* __restrict__ vT_g, const unsigned long long* __restrict__ mbits,
    float* __restrict__ out)
{
    const int qt = blockIdx.y;     // 0..7
    const int bh = blockIdx.x;     // 0..127 (bh-fast: same-bh qt-blocks are 128 apart -> same XCD)
    const int b = bh >> 3, head = bh & 7;
    const int tid = threadIdx.x, wave = tid >> 6, lane = tid & 63;
    const int quad = lane >> 4, ln = lane & 15;

    __shared__ __align__(16) unsigned char lds[34816];   // 4 waves x 8704 B, strictly per-wave
    unsigned char* wlds = lds + wave * 8704;

    // ===================== Phase Q: q' = (X Wq) * SCALE2, 3-term split =====================
    f32x4 qacc[2][4];
    #pragma unroll
    for (int rg = 0; rg < 2; ++rg)
        #pragma unroll
        for (int t = 0; t < 4; ++t) qacc[rg][t] = (f32x4){0.f, 0.f, 0.f, 0.f};

    const __bf16* WhiQ = Whi_t + (size_t)head * 2048 * 8;
    const __bf16* WloQ = Wlo_t + (size_t)head * 2048 * 8;

    #pragma unroll
    for (int kc = 0; kc < 8; ++kc) {
        bf16x8 ahi[2], alo[2];
        #pragma unroll
        for (int rg = 0; rg < 2; ++rg) {
            const float* xr = X + ((size_t)b * 1024 + qt * 128 + wave * 32 + rg * 16 + ln) * 256;
            f32x4 xa = *(const f32x4*)(xr + kc * 32 + quad * 8);
            f32x4 xb = *(const f32x4*)(xr + kc * 32 + quad * 8 + 4);
            #pragma unroll
            for (int j = 0; j < 4; ++j) {
                __bf16 h0 = (__bf16)xa[j]; ahi[rg][j] = h0; alo[rg][j] = (__bf16)(xa[j] - (float)h0);
                __bf16 h1 = (__bf16)xb[j]; ahi[rg][4 + j] = h1; alo[rg][4 + j] = (__bf16)(xb[j] - (float)h1);
            }
        }
        #pragma unroll
        for (int t = 0; t < 4; ++t) {
            size_t fo = (size_t)((kc * 4 + t) * 64 + lane) * 8;
            bf16x8 bhi = *(const bf16x8*)(WhiQ + fo);
            bf16x8 blo = *(const bf16x8*)(WloQ + fo);
            #pragma unroll
            for (int rg = 0; rg < 2; ++rg) {
                qacc[rg][t] = mfma16(ahi[rg], bhi, qacc[rg][t]);
                qacc[rg][t] = mfma16(alo[rg], bhi, qacc[rg][t]);
                qacc[rg][t] = mfma16(ahi[rg], blo, qacc[rg][t]);
            }
        }
    }

    // C-layout -> A-layout transpose via per-wave LDS (32 rows x 272 B)
    #pragma unroll
    for (int rg = 0; rg < 2; ++rg)
        #pragma unroll
        for (int t = 0; t < 4; ++t) {
            qacc[rg][t] *= SCALE2;
            #pragma unroll
            for (int r = 0; r < 4; ++r)
                *(float*)(wlds + (rg * 16 + quad * 4 + r) * 272 + (t * 16 + ln) * 4) =
                    qacc[rg][t][r];
        }
    asm volatile("s_waitcnt lgkmcnt(0)" ::: "memory");
    bf16x8 qhi[2][2], qlo[2][2];
    #pragma unroll
    for (int rg = 0; rg < 2; ++rg)
        #pragma unroll
        for (int c = 0; c < 2; ++c) {
            f32x4 a0 = *(const f32x4*)(wlds + (rg * 16 + ln) * 272 + c * 128 + quad * 32);
            f32x4 a1 = *(const f32x4*)(wlds + (rg * 16 + ln) * 272 + c * 128 + quad * 32 + 16);
            #pragma unroll
            for (int j = 0; j < 4; ++j) {
                __bf16 h0 = (__bf16)a0[j]; qhi[rg][c][j] = h0; qlo[rg][c][j] = (__bf16)(a0[j] - (float)h0);
                __bf16 h1 = (__bf16)a1[j]; qhi[rg][c][4 + j] = h1; qlo[rg][c][4 + j] = (__bf16)(a1[j] - (float)h1);
            }
        }
    asm volatile("s_waitcnt lgkmcnt(0)" ::: "memory");   // scratch reads done before P overlays

    // ===================== flash loop over 16 m-tiles — NO BARRIERS =====================
    int addrP[2];
    #pragma unroll
    for (int c = 0; c < 2; ++c)
        addrP[c] = ln * 128 + (((c * 4 + quad) ^ (ln & 7)) << 4);

    f32x4 o[2][4];
    float mrow[2][4], lrow[2][4];
    #pragma unroll
    for (int rg = 0; rg < 2; ++rg)
        #pragma unroll
        for (int t = 0; t < 4; ++t) {
            o[rg][t] = (f32x4){0.f, 0.f, 0.f, 0.f};
            mrow[rg][t] = -INFINITY; lrow[rg][t] = 0.f;   // [rg][r]
        }

    const int qrow0 = qt * 128 + wave * 32 + quad * 4;
    const unsigned char* mbase = (const unsigned char*)mbits + (size_t)qrow0 * 128;
    const int lo16 = lane * 16;

    for (int mt = 0; mt < 16; ++mt) {
        const size_t tb = (size_t)(bh * 16 + mt) * 8192;
        const unsigned char* Kh = khi_g + tb;
        const unsigned char* Kl = klo_g + tb;
        const unsigned char* Vb = vT_g + tb;

        // mask words (one base, imm offsets)
        uint2 wm[2][4];
        #pragma unroll
        for (int rg = 0; rg < 2; ++rg)
            #pragma unroll
            for (int r = 0; r < 4; ++r)
                wm[rg][r] = *(const uint2*)(mbase + rg * 2048 + r * 128 + mt * 8);

        // ---- S = q' K^T (3-term), K frags straight from L2 ----
        f32x4 s[2][4];
        #pragma unroll
        for (int rg = 0; rg < 2; ++rg)
            #pragma unroll
            for (int t = 0; t < 4; ++t) s[rg][t] = (f32x4){0.f, 0.f, 0.f, 0.f};
        #pragma unroll
        for (int t = 0; t < 4; ++t)
            #pragma unroll
            for (int c = 0; c < 2; ++c) {
                bf16x8 khi = *(const bf16x8*)(Kh + (t * 2 + c) * 1024 + lo16);
                bf16x8 klo = *(const bf16x8*)(Kl + (t * 2 + c) * 1024 + lo16);
                #pragma unroll
                for (int rg = 0; rg < 2; ++rg) {
                    s[rg][t] = mfma16(qhi[rg][c], khi, s[rg][t]);
                    s[rg][t] = mfma16(qlo[rg][c], khi, s[rg][t]);
                    s[rg][t] = mfma16(qhi[rg][c], klo, s[rg][t]);
                }
            }

        // early-issue V frags for c=0 (hidden under softmax)
        bf16x8 vf0[4];
        #pragma unroll
        for (int t = 0; t < 4; ++t)
            vf0[t] = *(const bf16x8*)(Vb + (t * 2) * 1024 + lo16);

        // ---- mask + online softmax (DPP) + P into per-wave LDS ----
        #pragma unroll
        for (int rg = 0; rg < 2; ++rg) {
            float pw[4][4], alpha[4];
            #pragma unroll
            for (int r = 0; r < 4; ++r) {
                float sv[4];
                #pragma unroll
                for (int t = 0; t < 4; ++t) {
                    unsigned bits = (t & 2) ? wm[rg][r].y : wm[rg][r].x;
                    float bit = (float)((bits >> ((t & 1) * 16 + ln)) & 1u);
                    sv[t] = fmaf(bit, NEGB, s[rg][t][r]);
                }
                float tm = fmaxf(fmaxf(sv[0], sv[1]), fmaxf(sv[2], sv[3]));
                tm = rowmax16(tm);
                float mn = fmaxf(mrow[rg][r], tm);
                float a = __builtin_amdgcn_exp2f(mrow[rg][r] - mn);
                float rs = 0.f;
                #pragma unroll
                for (int t = 0; t < 4; ++t) {
                    float p = __builtin_amdgcn_exp2f(sv[t] - mn);
                    pw[r][t] = p; rs += p;
                }
                rs = rowsum16(rs);
                lrow[rg][r] = lrow[rg][r] * a + rs;
                mrow[rg][r] = mn;
                alpha[r] = a;
            }
            #pragma unroll
            for (int t = 0; t < 4; ++t)
                #pragma unroll
                for (int r = 0; r < 4; ++r) o[rg][t][r] *= alpha[r];
            #pragma unroll
            for (int t = 0; t < 4; ++t) {
                int lc16 = t * 32 + ((ln >> 3) << 4);
                #pragma unroll
                for (int r = 0; r < 4; ++r) {
                    int row = quad * 4 + r;
                    int addr = rg * 2048 + row * 128 + (lc16 ^ ((row & 7) << 4)) + ((ln & 7) << 1);
                    *(__bf16*)(wlds + addr) = (__bf16)pw[r][t];
                }
            }
        }
        asm volatile("s_waitcnt lgkmcnt(0)" ::: "memory");   // same-wave P RAW

        // second half of V frags (c=1)
        bf16x8 vf1[4];
        #pragma unroll
        for (int t = 0; t < 4; ++t)
            vf1[t] = *(const bf16x8*)(Vb + (t * 2 + 1) * 1024 + lo16);

        // ---- O += P V ----
        #pragma unroll
        for (int c = 0; c < 2; ++c) {
            bf16x8 pa[2];
            #pragma unroll
            for (int rg = 0; rg < 2; ++rg)
                pa[rg] = *(const bf16x8*)(wlds + rg * 2048 + addrP[c]);
            #pragma unroll
            for (int t = 0; t < 4; ++t) {
                bf16x8 vb = c ? vf1[t] : vf0[t];
                #pragma unroll
                for (int rg = 0; rg < 2; ++rg) o[rg][t] = mfma16(pa[rg], vb, o[rg][t]);
            }
        }
    }

    // ---- epilogue ----
    float* ob = out + (size_t)bh * 65536;
    #pragma unroll
    for (int rg = 0; rg < 2; ++rg)
        #pragma unroll
        for (int r = 0; r < 4; ++r) {
            float inv = 1.0f / lrow[rg][r];
            #pragma unroll
            for (int t = 0; t < 4; ++t)
                ob[(size_t)(qrow0 + rg * 16 + r) * 64 + t * 16 + ln] = o[rg][t][r] * inv;
        }
}

extern "C" void kernel_launch(void* const* d_in, const int* in_sizes, int n_in,
                              void* d_out, int out_size, void* d_ws, size_t ws_size,
                              hipStream_t stream) {
    const float* h    = (const float*)d_in[0];   // [16,1024,256] fp32
    const int*   mask = (const int*)d_in[1];     // [1024,1024] int32
    const float* Wq   = (const float*)d_in[2];   // [8,256,64] fp32
    const float* Wk   = (const float*)d_in[3];
    const float* Wv   = (const float*)d_in[4];
    float* out = (float*)d_out;                  // [16,8,1024,64] fp32

    unsigned char* ws = (unsigned char*)d_ws;
    unsigned char* khi_g = ws;                                   // 16 MB
    unsigned char* klo_g = ws + 16777216;                        // 16 MB
    unsigned char* vT_g  = ws + 33554432;                        // 16 MB
    __bf16* Whi_t = (__bf16*)(ws + 50331648);                    // 768 KB
    __bf16* Wlo_t = (__bf16*)(ws + 51118080);                    // 768 KB
    unsigned long long* mbits = (unsigned long long*)(ws + 51904512); // 128 KB

    prep_kernel<<<1216, 256, 0, stream>>>(mask, Wq, Wk, Wv, mbits, Whi_t, Wlo_t);
    projkv_kernel<<<dim3(2, 256), 256, 0, stream>>>(h, Whi_t, Wlo_t, khi_g, klo_g, vT_g);
    attn_kernel<<<dim3(128, 8), 256, 0, stream>>>(h, Whi_t, Wlo_t, khi_g, klo_g, vT_g, mbits, out);
}

// Round 7
// 291.799 us; speedup vs baseline: 1.0276x; 1.0276x over previous
//
#include <hip/hip_runtime.h>
#include <math.h>

typedef __bf16 bf16x8 __attribute__((ext_vector_type(8)));
typedef float  f32x4  __attribute__((ext_vector_type(4)));

#define NEGB   (-1.4426950408889634e30f)   // -1e30 * log2(e)  (log2-domain mask value)
#define SCALE2 (0.18033688011112042f)      // (1/sqrt(64)) * log2(e), folded into q

static __device__ __forceinline__ f32x4 mfma16(bf16x8 a, bf16x8 b, f32x4 c) {
    return __builtin_amdgcn_mfma_f32_16x16x32_bf16(a, b, c, 0, 0, 0);
}

// DPP row_ror (within 16-lane rows) — VALU-only cross-lane, no DS pipe
template <int CTRL>
static __device__ __forceinline__ float dppf(float x) {
    int xi = __builtin_bit_cast(int, x);
    int r = __builtin_amdgcn_update_dpp(xi, xi, CTRL, 0xf, 0xf, false);
    return __builtin_bit_cast(float, r);
}
static __device__ __forceinline__ float rowmax16(float x) {
    x = fmaxf(x, dppf<0x128>(x));
    x = fmaxf(x, dppf<0x124>(x));
    x = fmaxf(x, dppf<0x122>(x));
    x = fmaxf(x, dppf<0x121>(x));
    return x;
}
static __device__ __forceinline__ float rowsum16(float x) {
    x += dppf<0x128>(x);
    x += dppf<0x124>(x);
    x += dppf<0x122>(x);
    x += dppf<0x121>(x);
    return x;
}

// ---------------- prep: mask -> bitmask, W -> hi/lo bf16 fragment order ----------------
__global__ void prep_kernel(const int* __restrict__ mask,
                            const float* __restrict__ Wq, const float* __restrict__ Wk,
                            const float* __restrict__ Wv,
                            unsigned long long* __restrict__ mbits,
                            __bf16* __restrict__ Whi_t, __bf16* __restrict__ Wlo_t)
{
    const int tid = threadIdx.x;
    if (blockIdx.x < 1024) {
        const int row = blockIdx.x, wave = tid >> 6, lane = tid & 63;
        #pragma unroll
        for (int i = 0; i < 4; ++i) {
            int word = wave * 4 + i;
            int m = mask[row * 1024 + word * 64 + lane];
            unsigned long long b = __ballot(m != 0);
            if (lane == 0) mbits[row * 16 + word] = b;
        }
    } else {
        int idx = (blockIdx.x - 1024) * 256 + tid;          // 0..49151
        int lane = idx & 63, t = (idx >> 6) & 3, kc = (idx >> 8) & 7;
        int head = (idx >> 11) & 7, mat = idx >> 14;
        int quad = lane >> 4, ln = lane & 15;
        const float* W = (mat == 0 ? Wq : (mat == 1 ? Wk : Wv)) + head * 16384;
        bf16x8 hi, lo;
        #pragma unroll
        for (int j = 0; j < 8; ++j) {
            float w = W[(kc * 32 + quad * 8 + j) * 64 + t * 16 + ln];
            __bf16 hh = (__bf16)w;
            hi[j] = hh;
            lo[j] = (__bf16)(w - (float)hh);
        }
        *(bf16x8*)(Whi_t + (size_t)idx * 8) = hi;
        *(bf16x8*)(Wlo_t + (size_t)idx * 8) = lo;
    }
}

// ---------------- projKV ----------------
// grid (8 head FAST, 256 rt, 2 mat): one 64-row tile, one head, K or V per block.
// Output tiles in attn B-FRAGMENT order: plane[bh][mt], 16B frag at (g*64+lane)*16.
__global__ __launch_bounds__(256, 2) void projkv_kernel(
    const float* __restrict__ X,
    const __bf16* __restrict__ Whi_t, const __bf16* __restrict__ Wlo_t,
    unsigned char* __restrict__ khi_g, unsigned char* __restrict__ klo_g,
    unsigned char* __restrict__ vT_g)
{
    const int head = blockIdx.x, rt = blockIdx.y, z = blockIdx.z;   // z: 0=K 1=V
    const int tid = threadIdx.x, wave = tid >> 6, lane = tid & 63;
    const int quad = lane >> 4, ln = lane & 15;

    __shared__ __align__(16) unsigned char SL[16384];   // K: hi|lo planes. V: first 8 KB.

    // X A-frags, hi/lo split (rows = rt*64 + wave*16 + ln); lo only needed for K
    const float* xr = X + ((size_t)(rt * 64 + wave * 16 + ln)) * 256;
    bf16x8 ahi[8], alo[8];
    #pragma unroll
    for (int kc = 0; kc < 8; ++kc) {
        f32x4 xa = *(const f32x4*)(xr + kc * 32 + quad * 8);
        f32x4 xb = *(const f32x4*)(xr + kc * 32 + quad * 8 + 4);
        #pragma unroll
        for (int j = 0; j < 4; ++j) {
            __bf16 h0 = (__bf16)xa[j]; ahi[kc][j] = h0; alo[kc][j] = (__bf16)(xa[j] - (float)h0);
            __bf16 h1 = (__bf16)xb[j]; ahi[kc][4 + j] = h1; alo[kc][4 + j] = (__bf16)(xb[j] - (float)h1);
        }
    }

    const int mat = 1 + z;
    const __bf16* Whi = Whi_t + ((size_t)(mat * 8 + head) * 2048) * 8;
    const __bf16* Wlo = Wlo_t + ((size_t)(mat * 8 + head) * 2048) * 8;

    f32x4 acc[4];
    #pragma unroll
    for (int t = 0; t < 4; ++t) acc[t] = (f32x4){0.f,0.f,0.f,0.f};

    #pragma unroll
    for (int kc = 0; kc < 8; ++kc) {
        #pragma unroll
        for (int t = 0; t < 4; ++t) {
            size_t fo = (size_t)((kc * 4 + t) * 64 + lane) * 8;
            bf16x8 bhi = *(const bf16x8*)(Whi + fo);
            acc[t] = mfma16(ahi[kc], bhi, acc[t]);
            if (z == 0) {
                bf16x8 blo = *(const bf16x8*)(Wlo + fo);
                acc[t] = mfma16(alo[kc], bhi, acc[t]);
                acc[t] = mfma16(ahi[kc], blo, acc[t]);
            }
        }
    }

    // assemble B-fragment-ordered tile(s) in LDS
    #pragma unroll
    for (int tp = 0; tp < 4; ++tp) {
        #pragma unroll
        for (int r = 0; r < 4; ++r) {
            if (z == 0) {   // K element (m = wave*16+quad*4+r, dk = tp*16+ln)
                float val = acc[tp][r];
                __bf16 hhv = (__bf16)val;
                __bf16 llv = (__bf16)(val - (float)hhv);
                int off = ((wave * 2 + (tp >> 1)) * 64 +
                           ((tp & 1) * 2 + (ln >> 3)) * 16 + quad * 4 + r) * 16 +
                          (ln & 7) * 2;
                *(__bf16*)(SL + off) = hhv;
                *(__bf16*)(SL + 8192 + off) = llv;
            } else {        // V element (m = wave*16+quad*4+r, dv = tp*16+ln)
                int off = ((tp * 2 + (wave >> 1)) * 64 +
                           ((wave & 1) * 2 + (quad >> 1)) * 16 + ln) * 16 +
                          ((quad & 1) * 4 + r) * 2;
                *(__bf16*)(SL + off) = (__bf16)acc[tp][r];
            }
        }
    }
    __syncthreads();

    const int bh = (rt >> 4) * 8 + head;
    const int mt = rt & 15;
    const size_t tb = (size_t)(bh * 16 + mt) * 8192;
    #pragma unroll
    for (int i = 0; i < 2; ++i) {
        int c = (i * 256 + tid) * 16;
        if (z == 0) {
            *(uint4*)(khi_g + tb + c) = *(const uint4*)(SL + c);
            *(uint4*)(klo_g + tb + c) = *(const uint4*)(SL + 8192 + c);
        } else {
            *(uint4*)(vT_g + tb + c) = *(const uint4*)(SL + c);
        }
    }
}

// ---------------- attn: fused Q-projection + flash attention, barrier-free, rg=1 ----------------
// block = 256 thr (4 waves x 16 q-rows), BM=64, grid (128 bh FAST, 16 qt)
__global__ __launch_bounds__(256) void attn_kernel(
    const float* __restrict__ X,
    const __bf16* __restrict__ Whi_t, const __bf16* __restrict__ Wlo_t,
    const unsigned char* __restrict__ khi_g, const unsigned char* __restrict__ klo_g,
    const unsigned char* __restrict__ vT_g, const unsigned long long* __restrict__ mbits,
    float* __restrict__ out)
{
    const int qt = blockIdx.y;     // 0..15
    const int bh = blockIdx.x;     // 0..127
    const int b = bh >> 3, head = bh & 7;
    const int tid = threadIdx.x, wave = tid >> 6, lane = tid & 63;
    const int quad = lane >> 4, ln = lane & 15;

    __shared__ __align__(16) unsigned char lds[18432];   // 4 waves x 4608 B, strictly per-wave
    unsigned char* wlds = lds + wave * 4608;

    // ===================== Phase Q: q' = (X Wq) * SCALE2, 3-term split =====================
    f32x4 qacc[4];
    #pragma unroll
    for (int t = 0; t < 4; ++t) qacc[t] = (f32x4){0.f, 0.f, 0.f, 0.f};

    const __bf16* WhiQ = Whi_t + (size_t)head * 2048 * 8;
    const __bf16* WloQ = Wlo_t + (size_t)head * 2048 * 8;
    const float* xr = X + ((size_t)b * 1024 + qt * 64 + wave * 16 + ln) * 256;

    #pragma unroll
    for (int kc = 0; kc < 8; ++kc) {
        f32x4 xa = *(const f32x4*)(xr + kc * 32 + quad * 8);
        f32x4 xb = *(const f32x4*)(xr + kc * 32 + quad * 8 + 4);
        bf16x8 ahi, alo;
        #pragma unroll
        for (int j = 0; j < 4; ++j) {
            __bf16 h0 = (__bf16)xa[j]; ahi[j] = h0; alo[j] = (__bf16)(xa[j] - (float)h0);
            __bf16 h1 = (__bf16)xb[j]; ahi[4 + j] = h1; alo[4 + j] = (__bf16)(xb[j] - (float)h1);
        }
        #pragma unroll
        for (int t = 0; t < 4; ++t) {
            size_t fo = (size_t)((kc * 4 + t) * 64 + lane) * 8;
            bf16x8 bhi = *(const bf16x8*)(WhiQ + fo);
            bf16x8 blo = *(const bf16x8*)(WloQ + fo);
            qacc[t] = mfma16(ahi, bhi, qacc[t]);
            qacc[t] = mfma16(alo, bhi, qacc[t]);
            qacc[t] = mfma16(ahi, blo, qacc[t]);
        }
    }

    // C-layout -> A-layout transpose via per-wave LDS (16 rows x 272 B)
    #pragma unroll
    for (int t = 0; t < 4; ++t) {
        qacc[t] *= SCALE2;
        #pragma unroll
        for (int r = 0; r < 4; ++r)
            *(float*)(wlds + (quad * 4 + r) * 272 + (t * 16 + ln) * 4) = qacc[t][r];
    }
    asm volatile("s_waitcnt lgkmcnt(0)" ::: "memory");
    bf16x8 qhi[2], qlo[2];
    #pragma unroll
    for (int c = 0; c < 2; ++c) {
        f32x4 a0 = *(const f32x4*)(wlds + ln * 272 + c * 128 + quad * 32);
        f32x4 a1 = *(const f32x4*)(wlds + ln * 272 + c * 128 + quad * 32 + 16);
        #pragma unroll
        for (int j = 0; j < 4; ++j) {
            __bf16 h0 = (__bf16)a0[j]; qhi[c][j] = h0; qlo[c][j] = (__bf16)(a0[j] - (float)h0);
            __bf16 h1 = (__bf16)a1[j]; qhi[c][4 + j] = h1; qlo[c][4 + j] = (__bf16)(a1[j] - (float)h1);
        }
    }
    asm volatile("s_waitcnt lgkmcnt(0)" ::: "memory");   // scratch reads done before P overlays

    // ===================== flash loop over 16 m-tiles =====================
    int addrP[2];
    #pragma unroll
    for (int c = 0; c < 2; ++c)
        addrP[c] = ln * 128 + (((c * 4 + quad) ^ (ln & 7)) << 4);

    f32x4 o[4];
    float mrow[4], lrow[4];
    #pragma unroll
    for (int t = 0; t < 4; ++t) {
        o[t] = (f32x4){0.f, 0.f, 0.f, 0.f};
        mrow[t] = -INFINITY; lrow[t] = 0.f;   // [r]
    }

    const int qrow0 = qt * 64 + wave * 16 + quad * 4;
    const unsigned char* mbase = (const unsigned char*)mbits + (size_t)qrow0 * 128;
    const int lo16 = lane * 16;

    for (int mt = 0; mt < 16; ++mt) {
        const size_t tb = (size_t)(bh * 16 + mt) * 8192;
        const unsigned char* Kh = khi_g + tb;
        const unsigned char* Kl = klo_g + tb;
        const unsigned char* Vb = vT_g + tb;

        uint2 wm[4];
        #pragma unroll
        for (int r = 0; r < 4; ++r)
            wm[r] = *(const uint2*)(mbase + r * 128 + mt * 8);

        // ---- S = q' K^T (3-term), K frags straight from L2 ----
        f32x4 s[4];
        #pragma unroll
        for (int t = 0; t < 4; ++t) s[t] = (f32x4){0.f, 0.f, 0.f, 0.f};
        #pragma unroll
        for (int t = 0; t < 4; ++t)
            #pragma unroll
            for (int c = 0; c < 2; ++c) {
                bf16x8 khi = *(const bf16x8*)(Kh + (t * 2 + c) * 1024 + lo16);
                bf16x8 klo = *(const bf16x8*)(Kl + (t * 2 + c) * 1024 + lo16);
                s[t] = mfma16(qhi[c], khi, s[t]);
                s[t] = mfma16(qlo[c], khi, s[t]);
                s[t] = mfma16(qhi[c], klo, s[t]);
            }

        // ---- mask + online softmax (DPP) + P into per-wave LDS ----
        float pw[4][4], alpha[4];
        #pragma unroll
        for (int r = 0; r < 4; ++r) {
            float sv[4];
            #pragma unroll
            for (int t = 0; t < 4; ++t) {
                unsigned bits = (t & 2) ? wm[r].y : wm[r].x;
                float bit = (float)((bits >> ((t & 1) * 16 + ln)) & 1u);
                sv[t] = fmaf(bit, NEGB, s[t][r]);
            }
            float tm = fmaxf(fmaxf(sv[0], sv[1]), fmaxf(sv[2], sv[3]));
            tm = rowmax16(tm);
            float mn = fmaxf(mrow[r], tm);
            float a = __builtin_amdgcn_exp2f(mrow[r] - mn);
            float rs = 0.f;
            #pragma unroll
            for (int t = 0; t < 4; ++t) {
                float p = __builtin_amdgcn_exp2f(sv[t] - mn);
                pw[r][t] = p; rs += p;
            }
            rs = rowsum16(rs);
            lrow[r] = lrow[r] * a + rs;
            mrow[r] = mn;
            alpha[r] = a;
        }
        #pragma unroll
        for (int t = 0; t < 4; ++t)
            #pragma unroll
            for (int r = 0; r < 4; ++r) o[t][r] *= alpha[r];
        #pragma unroll
        for (int t = 0; t < 4; ++t) {
            int lc16 = t * 32 + ((ln >> 3) << 4);
            #pragma unroll
            for (int r = 0; r < 4; ++r) {
                int row = quad * 4 + r;
                int addr = row * 128 + (lc16 ^ ((row & 7) << 4)) + ((ln & 7) << 1);
                *(__bf16*)(wlds + addr) = (__bf16)pw[r][t];
            }
        }
        asm volatile("s_waitcnt lgkmcnt(0)" ::: "memory");   // same-wave P RAW

        // ---- O += P V (V frags loaded inline, compiler pipelines) ----
        #pragma unroll
        for (int c = 0; c < 2; ++c) {
            bf16x8 pa = *(const bf16x8*)(wlds + addrP[c]);
            #pragma unroll
            for (int t = 0; t < 4; ++t) {
                bf16x8 vb = *(const bf16x8*)(Vb + (t * 2 + c) * 1024 + lo16);
                o[t] = mfma16(pa, vb, o[t]);
            }
        }
    }

    // ---- epilogue ----
    float* ob = out + (size_t)bh * 65536;
    #pragma unroll
    for (int r = 0; r < 4; ++r) {
        float inv = 1.0f / lrow[r];
        #pragma unroll
        for (int t = 0; t < 4; ++t)
            ob[(size_t)(qrow0 + r) * 64 + t * 16 + ln] = o[t][r] * inv;
    }
}

extern "C" void kernel_launch(void* const* d_in, const int* in_sizes, int n_in,
                              void* d_out, int out_size, void* d_ws, size_t ws_size,
                              hipStream_t stream) {
    const float* h    = (const float*)d_in[0];   // [16,1024,256] fp32
    const int*   mask = (const int*)d_in[1];     // [1024,1024] int32
    const float* Wq   = (const float*)d_in[2];   // [8,256,64] fp32
    const float* Wk   = (const float*)d_in[3];
    const float* Wv   = (const float*)d_in[4];
    float* out = (float*)d_out;                  // [16,8,1024,64] fp32

    unsigned char* ws = (unsigned char*)d_ws;
    unsigned char* khi_g = ws;                                   // 16 MB
    unsigned char* klo_g = ws + 16777216;                        // 16 MB
    unsigned char* vT_g  = ws + 33554432;                        // 16 MB
    __bf16* Whi_t = (__bf16*)(ws + 50331648);                    // 768 KB
    __bf16* Wlo_t = (__bf16*)(ws + 51118080);                    // 768 KB
    unsigned long long* mbits = (unsigned long long*)(ws + 51904512); // 128 KB

    prep_kernel<<<1216, 256, 0, stream>>>(mask, Wq, Wk, Wv, mbits, Whi_t, Wlo_t);
    projkv_kernel<<<dim3(8, 256, 2), 256, 0, stream>>>(h, Whi_t, Wlo_t, khi_g, klo_g, vT_g);
    attn_kernel<<<dim3(128, 16), 256, 0, stream>>>(h, Whi_t, Wlo_t, khi_g, klo_g, vT_g, mbits, out);
}